// Round 1
// baseline (106.244 us; speedup 1.0000x reference)
//
#include <hip/hip_runtime.h>
#include <hip/hip_bf16.h>
#include <hip/hip_fp16.h>

typedef _Float16 half8 __attribute__((ext_vector_type(8)));
typedef _Float16 half4 __attribute__((ext_vector_type(4)));
typedef float    floatx4 __attribute__((ext_vector_type(4)));
typedef unsigned int uintx4 __attribute__((ext_vector_type(4)));

#define BM 128
#define ZSTRIDE 264   // 256 + 8 halves -> row stride 528 B (2-way LDS aliasing = free)
#define WSTRIDE 72    // 64 + 8 halves  -> row stride 144 B (2-way)

// ---------------------------------------------------------------------------
// Kernel 1: W_l^T[n][k] = tri(||p_l[k] - p_{l+1}[n]||) / 16, fp16, layout [3][256][256]
// ---------------------------------------------------------------------------
__global__ void make_weights(const float* __restrict__ p0, const float* __restrict__ p1,
                             const float* __restrict__ p2, const float* __restrict__ p3,
                             _Float16* __restrict__ wt) {
    int idx = blockIdx.x * blockDim.x + threadIdx.x;   // (l*256 + n)*256 + k
    int k = idx & 255;
    int n = (idx >> 8) & 255;
    int l = idx >> 16;
    const float* P[4] = {p0, p1, p2, p3};
    const float* pa = P[l]     + k * 20;
    const float* pb = P[l + 1] + n * 20;
    float d2 = 0.0f;
    #pragma unroll
    for (int i = 0; i < 20; ++i) { float df = pa[i] - pb[i]; d2 += df * df; }
    float d = sqrtf(d2);
    float m = fmodf(d, 0.2f);                       // == np.mod for positive args
    float w = 10.0f * (0.05f - fabsf(m - 0.1f)) * 0.0625f;  // tri * 1/sqrt(256)
    wt[idx] = (_Float16)w;
}

// ---------------------------------------------------------------------------
// Kernel 2: fused 3-layer forward. One block = 128 rows of x, all 256 cols.
// 8 waves (2 row-tiles x 4 col-tiles of 64x64), mfma_f32_16x16x32_f16.
// z lives in LDS between layers; W chunks double-buffered from global (L2-resident).
// ---------------------------------------------------------------------------
__global__ __launch_bounds__(512, 2) void pcn_fused(
    const float* __restrict__ x, const _Float16* __restrict__ wt,
    const float* __restrict__ b1, const float* __restrict__ b2,
    const float* __restrict__ b3, float* __restrict__ out) {

    __shared__ __align__(16) _Float16 zlds[BM * ZSTRIDE];       // 67,584 B
    __shared__ __align__(16) _Float16 wlds[2][256 * WSTRIDE];   // 73,728 B  (total 141,312 B)

    const int t    = threadIdx.x;
    const int lane = t & 63;
    const int wid  = t >> 6;      // 0..7
    const int wr   = wid >> 2;    // 0..1  row-tile
    const int wc   = wid & 3;     // 0..3  col-tile
    const int l15  = lane & 15;
    const int lg   = lane >> 4;   // 0..3
    const size_t row0 = (size_t)blockIdx.x * BM;

    floatx4 xreg[4];
    uintx4  wreg[4];

    // --- staging: x chunk ks (layer 0 only): 128 rows x 64 cols f32 -> f16 ---
    auto stage_x_load = [&](int ks) {
        #pragma unroll
        for (int i = 0; i < 4; ++i) {
            int f = i * 512 + t;
            int row = f >> 4, col4 = f & 15;
            xreg[i] = *reinterpret_cast<const floatx4*>(
                x + (row0 + row) * 256 + ks * 64 + col4 * 4);
        }
    };
    auto stage_x_write = [&](int ks) {
        #pragma unroll
        for (int i = 0; i < 4; ++i) {
            int f = i * 512 + t;
            int row = f >> 4, col4 = f & 15;
            half4 h;
            h[0] = (_Float16)xreg[i][0]; h[1] = (_Float16)xreg[i][1];
            h[2] = (_Float16)xreg[i][2]; h[3] = (_Float16)xreg[i][3];
            *reinterpret_cast<half4*>(&zlds[row * ZSTRIDE + ks * 64 + col4 * 4]) = h;
        }
    };
    // --- staging: W chunk (l, ks): 256 rows(n) x 64 k fp16 ---
    auto stage_w_load = [&](int l, int ks) {
        const _Float16* wg = wt + ((size_t)l << 16) + ks * 64;
        #pragma unroll
        for (int i = 0; i < 4; ++i) {
            int f = i * 512 + t;
            int n = f >> 3, k8 = f & 7;
            wreg[i] = *reinterpret_cast<const uintx4*>(wg + (size_t)n * 256 + k8 * 8);
        }
    };
    auto stage_w_write = [&](int buf) {
        #pragma unroll
        for (int i = 0; i < 4; ++i) {
            int f = i * 512 + t;
            int n = f >> 3, k8 = f & 7;
            *reinterpret_cast<uintx4*>(&wlds[buf][n * WSTRIDE + k8 * 8]) = wreg[i];
        }
    };

    // prologue: x chunk 0 + W(0,0)
    stage_x_load(0);
    stage_w_load(0, 0);
    stage_x_write(0);
    stage_w_write(0);
    __syncthreads();

    floatx4 acc[4][4];

    for (int l = 0; l < 3; ++l) {
        #pragma unroll
        for (int mf = 0; mf < 4; ++mf)
            #pragma unroll
            for (int nf = 0; nf < 4; ++nf)
                acc[mf][nf] = floatx4{0.f, 0.f, 0.f, 0.f};

        for (int ks = 0; ks < 4; ++ks) {
            const int buf = ks & 1;
            // issue next-chunk global loads early (latency hides under MFMA)
            if (ks < 3) {
                stage_w_load(l, ks + 1);
                if (l == 0) stage_x_load(ks + 1);
            }
            // compute: K-chunk of 64 = 2 sub-steps of K=32
            #pragma unroll
            for (int kk = 0; kk < 2; ++kk) {
                half8 a[4], b[4];
                const int kz = ks * 64 + kk * 32 + lg * 8;
                const int kw = kk * 32 + lg * 8;
                #pragma unroll
                for (int mf = 0; mf < 4; ++mf)
                    a[mf] = *reinterpret_cast<const half8*>(
                        &zlds[(wr * 64 + mf * 16 + l15) * ZSTRIDE + kz]);
                #pragma unroll
                for (int nf = 0; nf < 4; ++nf)
                    b[nf] = *reinterpret_cast<const half8*>(
                        &wlds[buf][(wc * 64 + nf * 16 + l15) * WSTRIDE + kw]);
                #pragma unroll
                for (int mf = 0; mf < 4; ++mf)
                    #pragma unroll
                    for (int nf = 0; nf < 4; ++nf)
                        acc[mf][nf] = __builtin_amdgcn_mfma_f32_16x16x32_f16(
                            a[mf], b[nf], acc[mf][nf], 0, 0, 0);
            }
            // write next chunk to the other buffer (auto vmcnt wait before ds_write)
            if (ks < 3) {
                stage_w_write((ks + 1) & 1);
                if (l == 0) stage_x_write(ks + 1);
            }
            __syncthreads();
        }

        const float* bias = (l == 0) ? b1 : (l == 1) ? b2 : b3;
        if (l < 2) {
            // bias + relu + cast -> zlds (all waves finished reading zlds at last barrier)
            #pragma unroll
            for (int nf = 0; nf < 4; ++nf) {
                const int n = wc * 64 + nf * 16 + l15;
                const float bv = bias[n];
                #pragma unroll
                for (int mf = 0; mf < 4; ++mf) {
                    const int mrow = wr * 64 + mf * 16 + lg * 4;
                    #pragma unroll
                    for (int r = 0; r < 4; ++r) {
                        float v = acc[mf][nf][r] + bv;
                        v = fmaxf(v, 0.0f);
                        zlds[(mrow + r) * ZSTRIDE + n] = (_Float16)v;
                    }
                }
            }
            // stage first W chunk of next layer into buf 0
            stage_w_load(l + 1, 0);
            stage_w_write(0);
            __syncthreads();
        } else {
            // final layer: bias, no relu, f32 out
            #pragma unroll
            for (int nf = 0; nf < 4; ++nf) {
                const int n = wc * 64 + nf * 16 + l15;
                const float bv = bias[n];
                #pragma unroll
                for (int mf = 0; mf < 4; ++mf) {
                    const size_t mrow = row0 + wr * 64 + mf * 16 + lg * 4;
                    #pragma unroll
                    for (int r = 0; r < 4; ++r)
                        out[(mrow + r) * 256 + n] = acc[mf][nf][r] + bv;
                }
            }
        }
    }
}

extern "C" void kernel_launch(void* const* d_in, const int* in_sizes, int n_in,
                              void* d_out, int out_size, void* d_ws, size_t ws_size,
                              hipStream_t stream) {
    const float* x  = (const float*)d_in[0];
    const float* p0 = (const float*)d_in[1];
    const float* p1 = (const float*)d_in[2];
    const float* p2 = (const float*)d_in[3];
    const float* p3 = (const float*)d_in[4];
    const float* b1 = (const float*)d_in[5];
    const float* b2 = (const float*)d_in[6];
    const float* b3 = (const float*)d_in[7];
    float* out = (float*)d_out;
    _Float16* wt = (_Float16*)d_ws;              // 3*256*256*2 = 384 KB scratch

    const int B = in_sizes[0] / 256;             // 131072

    make_weights<<<3 * 256 * 256 / 256, 256, 0, stream>>>(p0, p1, p2, p3, wt);
    pcn_fused<<<B / BM, 512, 0, stream>>>(x, wt, b1, b2, b3, out);
}